// Round 13
// baseline (229.350 us; speedup 1.0000x reference)
//
#include <hip/hip_runtime.h>

// ---------------------------------------------------------------------------
// CustomMultiHeadAttentionStoich: fused MHA with RoPE + frac-difference bias.
// B=2 T=2048 D_MODEL=1024 H=16 hd=64. All matmuls via mfma_f32_16x16x32_bf16.
//
// Verified gfx950 fragment layouts (learn_hip m89/m91, rounds 1-6 pass):
//   A-frag : lane holds A[m=lane&15][k=(lane>>4)*8 + j], j=0..7  (8 bf16, 16B)
//   B-frag : lane holds B[k=(lane>>4)*8 + j][n=lane&15]
//   C/D    : lane holds D[row=(lane>>4)*4 + r][col=lane&15], r=0..3 (4 f32)
//
// Round-20: R12 got NO SIGNAL (infra: "MI355X container failed twice").
// Re-audited the key-split delta (grid bijection, key-range tiling, Pb/Lb
// dead-region placement + lifetimes, f16 partial precision, 160KiB LDS/CU,
// uniform barriers) -- no defect found. Resubmitting identical kernel:
//  * k_attn grid (16,32,2), z = key half; K-loop byte-identical to the
//    R8/R11-passing kernel. exp2-native no-max softmax => halves combine
//    exactly. Block writes locally-normalized O-hat (f16) + l (f32) into
//    dead workspace; k_attn_merge recombines (~5us).
//  * 1024 blocks = 4 blocks/CU x 8 waves = 32 waves/CU (HW cap).
//  * k_prep / k_gemm_qkv / k_gemm_out byte-identical to R11 (passing).
// ---------------------------------------------------------------------------

typedef unsigned short u16;
typedef __bf16 bf8v __attribute__((ext_vector_type(8)));
typedef __bf16 bf4v __attribute__((ext_vector_type(4)));
typedef float f32x4 __attribute__((ext_vector_type(4)));
typedef unsigned int u32x4v __attribute__((ext_vector_type(4)));
typedef _Float16 h8v __attribute__((ext_vector_type(8)));

#define D_MODEL 1024
#define T_SEQ   2048
#define NHEAD   16
#define HDIM    64
#define BATCH   2
#define M_TOT   (BATCH * T_SEQ) /* 4096 */
#define LOG2E   1.4426950408889634f

__device__ __forceinline__ void gl2lds16(const u16* g, u16* l) {
  __builtin_amdgcn_global_load_lds(
      (__attribute__((address_space(1))) void*)g,
      (__attribute__((address_space(3))) void*)l, 16, 0, 0);
}

// ---------------------------------------------------------------------------
// k_prep: zone-partitioned prep work in ONE launch.
//   blocks [0,6144)    : f32->bf16 convert of q/k/v into Xb
//   blocks [6144,7168) : W^T bf16 transpose of Wq/Wk/Wv/Wo into WtB
//   blocks [7168,7424) : RoPE cos/sin table
__global__ __launch_bounds__(256) void k_prep(
    const float* __restrict__ q, const float* __restrict__ k,
    const float* __restrict__ v, const float* __restrict__ Wq,
    const float* __restrict__ Wk, const float* __restrict__ Wv,
    const float* __restrict__ Wo, u16* __restrict__ Xb, u16* __restrict__ WtB,
    float* __restrict__ ct, float* __restrict__ st) {
  __shared__ float tile[64 * 65];
  int bx = blockIdx.x, tid = threadIdx.x;
  if (bx < 6144) { // ---- convert zone
    int z = bx >> 11, xb = bx & 2047;
    const float* src = (z == 0) ? q : (z == 1) ? k : v;
    u16* dst = Xb + (size_t)z * (M_TOT * D_MODEL);
    int idx = (xb * 256 + tid) * 8;
    float4 a = *(const float4*)(src + idx);
    float4 b = *(const float4*)(src + idx + 4);
    bf8v o;
    o[0] = (__bf16)a.x; o[1] = (__bf16)a.y; o[2] = (__bf16)a.z; o[3] = (__bf16)a.w;
    o[4] = (__bf16)b.x; o[5] = (__bf16)b.y; o[6] = (__bf16)b.z; o[7] = (__bf16)b.w;
    *(bf8v*)(dst + idx) = o;
  } else if (bx < 7168) { // ---- W transpose zone (64x64 tiles, stride 65)
    int idx2 = bx - 6144;
    int z = idx2 >> 8, rem = idx2 & 255;
    int k0 = (rem >> 4) * 64, n0 = (rem & 15) * 64;
    const float* W = (z == 0) ? Wq : (z == 1) ? Wk : (z == 2) ? Wv : Wo;
    u16* Wt = WtB + (size_t)z * (D_MODEL * D_MODEL);
#pragma unroll
    for (int i = 0; i < 16; i++) {
      int idx = tid + i * 256;
      int r = idx >> 6, c = idx & 63;
      tile[c * 65 + r] = W[(size_t)(k0 + r) * D_MODEL + n0 + c];
    }
    __syncthreads();
#pragma unroll
    for (int i = 0; i < 16; i++) {
      int idx = tid + i * 256;
      int r = idx >> 6, c = idx & 63;
      ((__bf16*)Wt)[(size_t)(n0 + r) * D_MODEL + k0 + c] = (__bf16)tile[r * 65 + c];
    }
  } else { // ---- RoPE table zone: angle(t,d) = t / 10000^(d/32)
    int idx = (bx - 7168) * 256 + tid; // = t*32 + d
    int t = idx >> 5, d = idx & 31;
    float ang = (float)t * powf(10000.0f, -(float)d * (1.0f / 32.0f));
    ct[idx] = cosf(ang);
    st[idx] = sinf(ang);
  }
}

// ---------------------------------------------------------------------------
// QKV GEMM core v3 (512 thr / 8 waves): C = A[M][K] @ Bt[N][K]^T, K=1024,
// BK=64, BM=BN=128. Wave w: rows (w>>1)*32..+32, cols (w&1)*64..+64.
// DOUBLE-buffered global_load_lds staging with counted vmcnt.
__device__ __forceinline__ void gemm_core_128x512(const u16* __restrict__ A,
                                                  const u16* __restrict__ Bt,
                                                  u16* sA, u16* sB,
                                                  f32x4 (&acc)[2][4],
                                                  int m0, int n0) {
  const int K = D_MODEL;
  const int NT = K / 64; // 16
  int tid = threadIdx.x;
  int lane = tid & 63, wave = tid >> 6;
  int l15 = lane & 15, quad = lane >> 4;
  int wm = (wave >> 1) * 32, wn = (wave & 1) * 64;
  int r0 = tid >> 2, pcol0 = (tid & 3) * 8; // row 0..127, col-chunk 0..3
  const u16* A0 = A + (size_t)(m0 + r0) * K + pcol0;
  const u16* B0 = Bt + (size_t)(n0 + r0) * K + pcol0;
  u16* dA = sA + wave * 512; // wave-uniform base; lane -> +lane*8 elems
  u16* dB = sB + wave * 512;
  auto stg = [&](int bo, int k0) {
    gl2lds16(A0 + k0, dA + bo);            // A plane0 (cols k0..k0+31)
    gl2lds16(A0 + k0 + 32, dA + 4096 + bo); // A plane1
    gl2lds16(B0 + k0, dB + bo);            // B plane0
    gl2lds16(B0 + k0 + 32, dB + 4096 + bo); // B plane1
  };
  stg(0, 0);
  for (int t = 0; t < NT; t++) {
    int bo = (t & 1) * 8192;
    __builtin_amdgcn_s_barrier(); // B1: all waves done reading buf[t-1]
    if (t + 1 < NT) {
      stg(bo ^ 8192, (t + 1) * 64);
      asm volatile("s_waitcnt vmcnt(4)" ::: "memory"); // stage(t) landed
    } else {
      asm volatile("s_waitcnt vmcnt(0)" ::: "memory"); // last: drain
    }
    __builtin_amdgcn_s_barrier(); // B2: all waves' stage(t) landed
#pragma unroll
    for (int kh = 0; kh < 2; kh++) {
      bf8v af[2], bf[4];
#pragma unroll
      for (int i = 0; i < 2; i++)
        af[i] = *(const bf8v*)(sA + bo + kh * 4096 + (wm + i * 16 + l15) * 32 + quad * 8);
#pragma unroll
      for (int i = 0; i < 4; i++)
        bf[i] = *(const bf8v*)(sB + bo + kh * 4096 + (wn + i * 16 + l15) * 32 + quad * 8);
#pragma unroll
      for (int mi = 0; mi < 2; mi++)
#pragma unroll
        for (int ni = 0; ni < 4; ni++)
          acc[mi][ni] = __builtin_amdgcn_mfma_f32_16x16x32_bf16(
              af[mi], bf[ni], acc[mi][ni], 0, 0, 0);
    }
  }
}

// QKV projection, grid (8, 32, 3), 512 thr. XCD-swizzled. z<2 -> RoPE fused;
// z==0 prescales Q by 0.125*log2e. z==2 writes V transposed into Vb.
__global__ __launch_bounds__(512, 2) void k_gemm_qkv(
    const u16* __restrict__ Xb, const u16* __restrict__ WtB,
    const float* __restrict__ bq, const float* __restrict__ bk,
    const float* __restrict__ bv, const float* __restrict__ ctab,
    const float* __restrict__ stab, u16* __restrict__ OutB,
    u16* __restrict__ Vb) {
  __shared__ __align__(16) u16 sA[2 * 128 * 64];
  __shared__ __align__(16) u16 sB[2 * 128 * 64];
  int z = blockIdx.z;
  const u16* A = Xb + (size_t)z * (M_TOT * D_MODEL);
  const u16* Bt = WtB + (size_t)z * (D_MODEL * D_MODEL);
  const float* bias = (z == 0) ? bq : (z == 1) ? bk : bv;
  u16* Out = OutB + (size_t)z * (M_TOT * D_MODEL);
  int mblk = (blockIdx.x << 2) | (blockIdx.y >> 3);
  int nblk = blockIdx.y & 7;
  int m0 = mblk * 128, n0 = nblk * 128;
  f32x4 acc[2][4] = {};
  gemm_core_128x512(A, Bt, sA, sB, acc, m0, n0);

  int tid = threadIdx.x, lane = tid & 63, wave = tid >> 6;
  int l15 = lane & 15, quad = lane >> 4;
  int wm = (wave >> 1) * 32, wn = (wave & 1) * 64;
  float bvv[4];
#pragma unroll
  for (int ni = 0; ni < 4; ni++) bvv[ni] = bias[n0 + wn + ni * 16 + l15];

  if (z < 2) { // Q/K: RoPE fused; Q also prescaled 0.125*log2e
    float qs = (z == 0) ? 0.125f * LOG2E : 1.0f;
#pragma unroll
    for (int mi = 0; mi < 2; mi++) {
#pragma unroll
      for (int r = 0; r < 4; r++) {
        int m = m0 + wm + mi * 16 + quad * 4 + r; // global row = b*T + t
        size_t ro = (size_t)m * D_MODEL + n0 + wn;
        int tl = m & (T_SEQ - 1);
#pragma unroll
        for (int ni = 0; ni < 2; ni++) {
          int d = ni * 16 + l15; // < 32; pair (d, d+32) in regs ni, ni+2
          float c = ctab[tl * 32 + d], s = stab[tl * 32 + d];
          float xl = acc[mi][ni][r] + bvv[ni];
          float xr = acc[mi][ni + 2][r] + bvv[ni + 2];
          ((__bf16*)Out)[ro + d] = (__bf16)((xl * c - xr * s) * qs);
          ((__bf16*)Out)[ro + d + 32] = (__bf16)((xl * s + xr * c) * qs);
        }
      }
    }
  } else { // V: write transposed Vb[b][h][d][t] (wave's 64 cols = one head)
    int hh = (n0 + wn) >> 6;
    int mbase = m0 + wm;
    int bb = mbase >> 11; // tile never crosses batch (2048 % 128 == 0)
    int tbase = mbase & (T_SEQ - 1);
    u16* Vw = Vb + (size_t)(bb * NHEAD + hh) * HDIM * T_SEQ;
#pragma unroll
    for (int mi = 0; mi < 2; mi++)
#pragma unroll
      for (int r = 0; r < 4; r++) {
        int t = tbase + mi * 16 + quad * 4 + r;
#pragma unroll
        for (int ni = 0; ni < 4; ni++) {
          int d = ni * 16 + l15;
          ((__bf16*)Vw)[(size_t)d * T_SEQ + t] = (__bf16)(acc[mi][ni][r] + bvv[ni]);
        }
      }
  }
}

// Output projection v2: ctx bf16 @ Wo^T + bo -> f32 d_out. 64x64 tiles,
// grid (16, 64) = 1024 blocks XCD-swizzled, 512 thr = 8 waves -> 4 blocks/CU
// = 32 waves/CU. Swizzled single-tile-per-operand staging (vmcnt(2)).
__global__ __launch_bounds__(512, 4) void k_gemm_out(
    const u16* __restrict__ ctx, const u16* __restrict__ Wot,
    const float* __restrict__ bo, float* __restrict__ Cout) {
  __shared__ __align__(16) u16 sA[2 * 64 * 64];
  __shared__ __align__(16) u16 sB[2 * 64 * 64];
  const int K = D_MODEL;
  const int NT = K / 64; // 16
  int xcd = blockIdx.x & 7;
  int idx = ((blockIdx.x >> 3) << 6) | blockIdx.y; // 0..127
  int m0 = (xcd * 8 + (idx >> 4)) * 64;
  int n0 = (idx & 15) * 64;
  int tid = threadIdx.x, lane = tid & 63, wave = tid >> 6;
  int l15 = lane & 15, quad = lane >> 4;
  int wm = (wave & 3) * 16, wn = (wave >> 2) * 32;
  int r0 = tid >> 3, gc0 = (tid & 7) ^ (r0 & 7);
  const u16* A0 = ctx + (size_t)(m0 + r0) * K + gc0 * 8;
  const u16* B0 = Wot + (size_t)(n0 + r0) * K + gc0 * 8;
  u16* dA = sA + wave * 512;
  u16* dB = sB + wave * 512;
  auto stg = [&](int bo_, int k0) {
    gl2lds16(A0 + k0, dA + bo_);
    gl2lds16(B0 + k0, dB + bo_);
  };
  int xa = (quad ^ (l15 & 7)) * 8;
  int aidx = (wm + l15) * 64 + xa;
  int bidx[2];
#pragma unroll
  for (int i = 0; i < 2; i++) bidx[i] = (wn + i * 16 + l15) * 64 + xa;

  f32x4 acc[2] = {};
  stg(0, 0);
  for (int t = 0; t < NT; t++) {
    int bo_ = (t & 1) * 4096;
    __builtin_amdgcn_s_barrier();
    if (t + 1 < NT) {
      stg(bo_ ^ 4096, (t + 1) * 64);
      asm volatile("s_waitcnt vmcnt(2)" ::: "memory");
    } else {
      asm volatile("s_waitcnt vmcnt(0)" ::: "memory");
    }
    __builtin_amdgcn_s_barrier();
#pragma unroll
    for (int kh = 0; kh < 2; kh++) {
      int xk = kh * 32;
      bf8v af = *(const bf8v*)(sA + bo_ + (aidx ^ xk));
      bf8v bf[2];
#pragma unroll
      for (int i = 0; i < 2; i++)
        bf[i] = *(const bf8v*)(sB + bo_ + (bidx[i] ^ xk));
#pragma unroll
      for (int ni = 0; ni < 2; ni++)
        acc[ni] = __builtin_amdgcn_mfma_f32_16x16x32_bf16(af, bf[ni],
                                                          acc[ni], 0, 0, 0);
    }
  }
  float bvv[2];
#pragma unroll
  for (int ni = 0; ni < 2; ni++) bvv[ni] = bo[n0 + wn + ni * 16 + l15];
#pragma unroll
  for (int r = 0; r < 4; r++) {
    size_t ro = (size_t)(m0 + wm + quad * 4 + r) * D_MODEL + n0 + wn;
#pragma unroll
    for (int ni = 0; ni < 2; ni++)
      Cout[ro + ni * 16 + l15] = acc[ni][r] + bvv[ni];
  }
}

// ---------------------------------------------------------------------------
// Flash attention v14 (key-split): grid (16 q-slots, 32 bh, 2 key-halves),
// 512 thr = 8 waves, q-tile 128. Wave w: q sub-tile qw = w&3, key half
// kh = w>>2 WITHIN the block's 1024-key range. K-loop byte-identical to the
// R8/R11-passing kernel; only kt range depends on z. exp2-native no-max
// softmax => all partials combine exactly. Block output: locally-normalized
// O-hat (f16) + l (f32) to workspace; k_attn_merge combines the two halves.
// 1024 blocks = 4 blocks/CU = 32 waves/CU; LDS 4x40960B = 160KiB/CU exact.
__global__ __launch_bounds__(512, 4) void k_attn(
    const u16* __restrict__ Qr, const u16* __restrict__ Kr,
    const u16* __restrict__ Vb, const float* __restrict__ frac,
    const float* __restrict__ alpha_pos, const float* __restrict__ alpha_neg,
    u16* __restrict__ Pb, float* __restrict__ Lb) {
  // smem carve (u16 elems):
  //   [0,8192)       kT[2][4096]  swizzled [key][d]
  //   [8192,16384)   vT[2][4096]  swizzled [d][key]
  //   [16384,20480)  fLds: f32[2048] frac row for this batch
  // merge phase reuses [0,16896) as f32 O-scratch, [16896,17152) l-scratch.
  __shared__ __align__(16) u16 smem[20480];
  // ---- XCD swizzle: lin%8 = XCD. Each XCD: 4 whole heads x (16 q x 2 z)
  // -> K/V (+Q) of those heads stay L2-resident on that XCD.
  int lin = blockIdx.x + (blockIdx.y << 4) + (blockIdx.z << 9);
  int xcd = lin & 7, slot = lin >> 3; // slot in [0,128)
  int bh = (xcd << 2) | (slot >> 5);
  int s5 = slot & 31;
  int q0 = (s5 & 15) << 7;
  int z = s5 >> 4; // key half: keys [z*1024, z*1024+1024)
  int b = bh >> 4, h = bh & 15;
  int tid = threadIdx.x, wave = tid >> 6, lane = tid & 63;
  int l15 = lane & 15, quad = lane >> 4;
  int qw = wave & 3;  // q sub-tile (32 rows)
  int kh = wave >> 2; // key half within each 64-key tile

  const u16* Kh = Kr + (size_t)b * T_SEQ * D_MODEL + h * HDIM;
  const u16* Vh = Vb + (size_t)bh * HDIM * T_SEQ;
  const float* fb = frac + b * T_SEQ;

  u16* kT0 = smem;
  u16* vT0 = smem + 8192;
  float* fl = (float*)(smem + 16384);

  // Q B-frags (B[k=d][n=q] = Q[q][d]): lane holds Q[q=l15][d=quad*8+j]
  bf8v qf[2][2];
  float fq[2];
#pragma unroll
  for (int g = 0; g < 2; g++) {
    int qrow = q0 + qw * 32 + g * 16 + l15;
    const u16* qbase =
        Qr + (size_t)(b * T_SEQ + qrow) * D_MODEL + h * HDIM + quad * 8;
    qf[g][0] = *(const bf8v*)qbase;
    qf[g][1] = *(const bf8v*)(qbase + 32);
    fq[g] = fb[qrow]; // S^T col = q = l15
  }
  // frac -> LDS (512 thr x 4 floats = 2048)
  {
    f32x4 fv = *(const f32x4*)(fb + (tid << 2));
    *(f32x4*)(fl + (tid << 2)) = fv;
  }

  // bias = ap*max(dd,0)+an*min(dd,0) = c1*dd + c2*|dd| (log2 domain)
  float ap = alpha_pos[h] * LOG2E, an = alpha_neg[h] * LOG2E;
  float c1 = 0.5f * (ap + an), c2 = 0.5f * (ap - an);
  bf8v onesv;
#pragma unroll
  for (int j = 0; j < 8; j++) onesv[j] = (__bf16)1.0f;
  f32x4 zero4 = {};
  f32x4 o[2][4] = {};
  f32x4 o_l[2] = {};

  // Hoisted frag offsets (elems). Swizzle: row r, chunk gc -> pc = gc^(r&7).
  int x0 = (quad ^ (l15 & 7)) * 8;
  int kidx[2], vidx[4];
#pragma unroll
  for (int nt = 0; nt < 2; nt++) // K rows kh*32 + nt*16 + l15
    kidx[nt] = (((kh * 2 + nt) * 16 + l15) << 6) + x0;
#pragma unroll
  for (int dt = 0; dt < 4; dt++) // V keys chunk quad + kh*4
    vidx[dt] = (((dt * 16 + l15) << 6) + x0) ^ (kh * 32);

  // DMA staging map: 512 threads x 1 chunk per array per tile.
  // chunk p = tid; row = p>>3, pc = p&7; fetch global chunk gc = pc^(row&7).
  int kr0 = tid >> 3, gc0 = (tid & 7) ^ (kr0 & 7);
  const u16* kg0 = Kh + (size_t)kr0 * D_MODEL + gc0 * 8;
  const u16* vg0 = Vh + (size_t)kr0 * T_SEQ + gc0 * 8; // row = d here
  int woff = wave * 512; // wave-uniform LDS dest (elems); lane -> +lane*8

  auto stage = [&](int bufoff, int kbase) {
    gl2lds16(kg0 + (size_t)kbase * D_MODEL, kT0 + bufoff + woff);
    gl2lds16(vg0 + kbase, vT0 + bufoff + woff);
  };

  int kstart = z << 10; // z*1024
  stage(0, kstart);
  __syncthreads(); // DMA + frac-LDS visible

#pragma unroll 2
  for (int kt = 0; kt < 16; kt++) {
    int kbase = kstart + kt * 64;
    int bo = (kt & 1) * 4096;
    if (kt + 1 < 16) stage(bo ^ 4096, kbase + 64);
    const u16* kb = kT0 + bo;
    const u16* vb = vT0 + bo;

    // K A-frags for this wave's key half: rows kh*32 + nt*16 + l15
    bf8v kf0[2], kf1[2];
#pragma unroll
    for (int nt = 0; nt < 2; nt++) {
      kf0[nt] = *(const bf8v*)(kb + kidx[nt]);
      kf1[nt] = *(const bf8v*)(kb + (kidx[nt] ^ 32));
    }
    // V B-frags: rows d = dt*16+l15; key chunks kh*4 + quad
    bf8v vf[4];
#pragma unroll
    for (int dt = 0; dt < 4; dt++) vf[dt] = *(const bf8v*)(vb + vidx[dt]);
    // frac[key] for this lane's 4 keys per nt (LDS, 16-lane broadcast)
    f32x4 fk4[2];
#pragma unroll
    for (int nt = 0; nt < 2; nt++)
      fk4[nt] = *(const f32x4*)(fl + kbase + kh * 32 + nt * 16 + quad * 4);

#pragma unroll
    for (int g = 0; g < 2; g++) {
      float fqg = fq[g];
      // wrd = [A0, A1, B0, B1]: A_m from nt0 keys {4q+2m,+1}, B_m from nt1.
      unsigned int wrd[4];
#pragma unroll
      for (int nt = 0; nt < 2; nt++) {
        // S^T tile: D[row=key_loc=nt*16+quad*4+r][col=q=l15], log2 domain
        f32x4 s = zero4;
        s = __builtin_amdgcn_mfma_f32_16x16x32_bf16(kf0[nt], qf[g][0], s, 0, 0, 0);
        s = __builtin_amdgcn_mfma_f32_16x16x32_bf16(kf1[nt], qf[g][1], s, 0, 0, 0);
        float p[4];
#pragma unroll
        for (int r = 0; r < 4; r++) {
          float dd = fk4[nt][r] - fqg;
          p[r] = __builtin_amdgcn_exp2f(
              fmaf(c2, __builtin_fabsf(dd), fmaf(c1, dd, s[r])));
        }
        unsigned int w0, w1;
        asm("v_cvt_pk_bf16_f32 %0, %1, %2" : "=v"(w0) : "v"(p[0]), "v"(p[1]));
        asm("v_cvt_pk_bf16_f32 %0, %1, %2" : "=v"(w1) : "v"(p[2]), "v"(p[3]));
        wrd[nt * 2 + 0] = w0;
        wrd[nt * 2 + 1] = w1;
      }
      // In-register P transpose. permlane32_swap: X'={Xq0,Xq1,Yq0,Yq1},
      // Y'={Xq2,Xq3,Yq2,Yq3}. permlane16_swap: X''={X'r0,Y'r0,X'r2,Y'r2},
      // Y''={X'r1,Y'r1,X'r3,Y'r3}. (A0,B0)->(W0,W2); (A1,B1)->(W1,W3):
      // lane quad q ends with keys {8q..8q+7} = PV A-frag for m=l15.
      // s_nop guards: VALU-write -> cross-lane-read wait states are NOT
      // auto-inserted across inline-asm boundaries by LLVM (R7/R8-proven).
      asm volatile("s_nop 1" ::: "memory"); // cvt_pk writes -> permlane reads
      asm("v_permlane32_swap_b32 %0, %1" : "+v"(wrd[0]), "+v"(wrd[2]));
      asm("v_permlane32_swap_b32 %0, %1" : "+v"(wrd[1]), "+v"(wrd[3]));
      asm volatile("s_nop 1" ::: "memory"); // permlane32 -> dependent permlane16
      asm("v_permlane16_swap_b32 %0, %1" : "+v"(wrd[0]), "+v"(wrd[2]));
      asm("v_permlane16_swap_b32 %0, %1" : "+v"(wrd[1]), "+v"(wrd[3]));
      asm volatile("s_nop 1" ::: "memory"); // permlane16 -> MFMA src read
      u32x4v pw_;
      pw_.x = wrd[0]; pw_.y = wrd[1]; pw_.z = wrd[2]; pw_.w = wrd[3];
      bf8v pf = __builtin_bit_cast(bf8v, pw_);
      // O_g += P_g @ V_half ; l_g += P_g @ ones.
      o_l[g] = __builtin_amdgcn_mfma_f32_16x16x32_bf16(pf, onesv, o_l[g], 0, 0, 0);
#pragma unroll
      for (int dt = 0; dt < 4; dt++)
        o[g][dt] = __builtin_amdgcn_mfma_f32_16x16x32_bf16(pf, vf[dt],
                                                           o[g][dt], 0, 0, 0);
    }
    __syncthreads(); // drains this iter's DMA (vmcnt) + frees cur buf
  }

  // ---- merge key halves within the block (kh), then write the block's
  // locally-normalized partial: O-hat = O/l as f16, l as f32.
  float* Of = (float*)smem;             // [128 q][66] f32 = 33792 B
  float* Lf = (float*)(smem + 16896);   // 128 f32
  if (kh == 1) {
#pragma unroll
    for (int g = 0; g < 2; g++)
#pragma unroll
      for (int r = 0; r < 4; r++) {
        int ql = qw * 32 + g * 16 + quad * 4 + r;
#pragma unroll
        for (int dt = 0; dt < 4; dt++)
          Of[ql * 66 + dt * 16 + l15] = o[g][dt][r];
        if (l15 == 0) Lf[ql] = o_l[g][r];
      }
  }
  __syncthreads();
  if (kh == 0) {
#pragma unroll
    for (int g = 0; g < 2; g++)
#pragma unroll
      for (int r = 0; r < 4; r++) {
        int ql = qw * 32 + g * 16 + quad * 4 + r;
        float lsum = o_l[g][r] + Lf[ql];
        float linv = 1.0f / lsum;
        int qglob = q0 + ql;
        size_t prow = ((size_t)(z * 32 + bh) * T_SEQ + qglob) * HDIM;
        _Float16* po = (_Float16*)Pb + prow;
#pragma unroll
        for (int dt = 0; dt < 4; dt++)
          po[dt * 16 + l15] =
              (_Float16)((o[g][dt][r] + Of[ql * 66 + dt * 16 + l15]) * linv);
        if (l15 == 0) Lb[(size_t)(z * 32 + bh) * T_SEQ + qglob] = lsum;
      }
  }
}

// k_attn_merge: ctx[bh][q][:] = (l0*O0 + l1*O1)/(l0+l1) in bf16.
// grid 1024 x 256 thr; thread t: row = t>>2 (bh*2048+q), dseg = (t&3)*16.
__global__ __launch_bounds__(256) void k_attn_merge(
    const u16* __restrict__ Pb, const float* __restrict__ Lb,
    u16* __restrict__ ctx) {
  int t = blockIdx.x * 256 + threadIdx.x; // [0, 262144)
  int row = t >> 2;                       // [0, 65536) = bh*2048 + q
  int dseg = (t & 3) * 16;
  int bh = row >> 11, q = row & 2047;
  int b = bh >> 4, h = bh & 15;
  float l0 = Lb[row], l1 = Lb[65536 + row];
  float w0 = l0 / (l0 + l1), w1 = 1.0f - w0;
  const _Float16* p0 = (const _Float16*)Pb + (size_t)row * HDIM + dseg;
  const _Float16* p1 = p0 + (size_t)65536 * HDIM;
  h8v a0 = *(const h8v*)p0, a1 = *(const h8v*)(p0 + 8);
  h8v b0 = *(const h8v*)p1, b1 = *(const h8v*)(p1 + 8);
  bf8v o0, o1;
#pragma unroll
  for (int j = 0; j < 8; j++) {
    o0[j] = (__bf16)(w0 * (float)a0[j] + w1 * (float)b0[j]);
    o1[j] = (__bf16)(w0 * (float)a1[j] + w1 * (float)b1[j]);
  }
  __bf16* orow = (__bf16*)ctx + (size_t)(b * T_SEQ + q) * D_MODEL + h * HDIM + dseg;
  *(bf8v*)orow = o0;
  *(bf8v*)(orow + 8) = o1;
}

// ---------------------------------------------------------------------------
extern "C" void kernel_launch(void* const* d_in, const int* in_sizes, int n_in,
                              void* d_out, int out_size, void* d_ws,
                              size_t ws_size, hipStream_t stream) {
  const float* q = (const float*)d_in[0];
  const float* k = (const float*)d_in[1];
  const float* v = (const float*)d_in[2];
  const float* frac = (const float*)d_in[3];
  const float* Wq = (const float*)d_in[4];
  const float* Wk = (const float*)d_in[5];
  const float* Wv = (const float*)d_in[6];
  const float* Wo = (const float*)d_in[7];
  const float* bq = (const float*)d_in[8];
  const float* bk = (const float*)d_in[9];
  const float* bv = (const float*)d_in[10];
  const float* bo = (const float*)d_in[11];
  const float* alpha_pos = (const float*)d_in[12];
  const float* alpha_neg = (const float*)d_in[13];

  char* ws = (char*)d_ws;
  u16* Xb = (u16*)(ws + 0);
  u16* Wt = (u16*)(ws + 25165824);
  u16* Qr = (u16*)(ws + 33554432);
  u16* Kr = (u16*)(ws + 41943040);
  u16* Vtmp = (u16*)(ws + 50331648); // holds ctx
  u16* Vb = (u16*)(ws + 58720256);
  float* ctab = (float*)(ws + 67108864);
  float* stab = (float*)(ws + 67371008);
  u16* ctx = Vtmp;
  u16* QKVout = Qr; // Qr,Kr contiguous; z==2 writes Vb directly
  // Attention partials reuse DEAD regions (after k_gemm_qkv):
  //   Pb (f16, 2 x 32bh x 2048q x 64d = 16.8MB) -> Xb region [0, 24MB)
  //   Lb (f32, 2 x 65536 = 512KB)               -> dead Wq^T slot
  u16* Pb = (u16*)(ws + 0);
  float* Lb = (float*)(ws + 25165824);

  k_prep<<<dim3(7424), 256, 0, stream>>>(q, k, v, Wq, Wk, Wv, Wo, Xb, Wt, ctab,
                                         stab);
  k_gemm_qkv<<<dim3(8, 32, 3), 512, 0, stream>>>(Xb, Wt, bq, bk, bv, ctab, stab,
                                                 QKVout, Vb);
  k_attn<<<dim3(16, 32, 2), 512, 0, stream>>>(Qr, Kr, Vb, frac, alpha_pos,
                                              alpha_neg, Pb, Lb);
  k_attn_merge<<<dim3(1024), 256, 0, stream>>>(Pb, Lb, ctx);
  k_gemm_out<<<dim3(16, 64), 512, 0, stream>>>(ctx, Wt + 3 * 1048576, bo,
                                               (float*)d_out);
}